// Round 2
// baseline (1618.868 us; speedup 1.0000x reference)
//
#include <hip/hip_runtime.h>
#include <hip/hip_bf16.h>

// Problem: L=4, N=256 queries, M=51200 gallery, D=1024.
// Inputs fp32 (per reference setup_inputs), output fp32 [1,1,16,16] = 256 floats.
// out[n] = 1 - mean_l max_m cos(q[l,n], g[l,m]),  eps=1e-8 on norms.
// Internals: bf16 MFMA (harness compares vs bf16-quantized ref, 2% rel tol).

#define L_LAYERS 4
#define N_Q 256
#define M_G 51200
#define K_D 1024
#define BM 64
#define NCHUNK (M_G / BM)   // 800

typedef __bf16 bf16x8 __attribute__((ext_vector_type(8)));
typedef float  f32x4  __attribute__((ext_vector_type(4)));

__device__ __forceinline__ bf16x8 cvt8(f32x4 a, f32x4 b) {
    bf16x8 r;
    r[0] = (__bf16)a[0]; r[1] = (__bf16)a[1]; r[2] = (__bf16)a[2]; r[3] = (__bf16)a[3];
    r[4] = (__bf16)b[0]; r[5] = (__bf16)b[1]; r[6] = (__bf16)b[2]; r[7] = (__bf16)b[3];
    return r;
}

// ---------------- Q inverse-norm prepass: 1024 rows, one wave per row ----
__global__ __launch_bounds__(64) void qnorm_kernel(const float* __restrict__ q,
                                                   float* __restrict__ invq) {
    const int row  = blockIdx.x;          // 0..1023 (= l*256+n)
    const int lane = threadIdx.x;         // 0..63
    const f32x4* p = (const f32x4*)(q + (size_t)row * K_D) + lane * 4;
    float ss = 0.f;
#pragma unroll
    for (int i = 0; i < 4; ++i) {
        f32x4 v = p[i];
        ss += v[0]*v[0] + v[1]*v[1] + v[2]*v[2] + v[3]*v[3];
    }
#pragma unroll
    for (int off = 32; off >= 1; off >>= 1) ss += __shfl_xor(ss, off, 64);
    if (lane == 0) invq[row] = 1.f / fmaxf(sqrtf(ss), 1e-8f);
}

// ---------------- main: register-direct MFMA, fp32->bf16 inline, no LDS ---
__global__ __launch_bounds__(256, 2) void sim_kernel(const float* __restrict__ Q,
                                                     const float* __restrict__ G,
                                                     const float* __restrict__ invq,
                                                     float* __restrict__ cmax) {
    const int c    = blockIdx.x;          // m-chunk 0..799
    const int l    = blockIdx.y;          // layer 0..3
    const int wave = threadIdx.x >> 6;    // 0..3
    const int lane = threadIdx.x & 63;
    const int qd   = lane >> 4;           // quad 0..3
    const int cc   = lane & 15;

    const int m0 = c * BM;
    const int n0 = wave * 64;

    // A frag rows: n = n0 + tn*16 + cc ; k = ks*32 + qd*8 + j  (32B contiguous fp32)
    const float* Ab = Q + ((size_t)l * N_Q + n0 + cc) * K_D + qd * 8;
    // B frag cols: m = m0 + tm*16 + cc ; same k pattern (row-major G == B^T layout)
    const float* Bb = G + ((size_t)l * M_G + m0 + cc) * K_D + qd * 8;

    f32x4 acc[4][4];            // [tn][tm] : C[n][m] raw bf16-dot products
    float gss[4] = {0.f, 0.f, 0.f, 0.f};   // partial sumsq of gallery rows (fp32)
#pragma unroll
    for (int tn = 0; tn < 4; ++tn)
#pragma unroll
        for (int tm = 0; tm < 4; ++tm) acc[tn][tm] = (f32x4){0.f, 0.f, 0.f, 0.f};

    for (int ks = 0; ks < K_D / 32; ++ks) {
        const int ko = ks * 32;
        bf16x8 afr[4], bfr[4];
#pragma unroll
        for (int tn = 0; tn < 4; ++tn) {
            f32x4 a = *(const f32x4*)(Ab + (size_t)(tn * 16) * K_D + ko);
            f32x4 b = *(const f32x4*)(Ab + (size_t)(tn * 16) * K_D + ko + 4);
            afr[tn] = cvt8(a, b);
        }
#pragma unroll
        for (int tm = 0; tm < 4; ++tm) {
            f32x4 a = *(const f32x4*)(Bb + (size_t)(tm * 16) * K_D + ko);
            f32x4 b = *(const f32x4*)(Bb + (size_t)(tm * 16) * K_D + ko + 4);
            bfr[tm] = cvt8(a, b);
            gss[tm] += a[0]*a[0] + a[1]*a[1] + a[2]*a[2] + a[3]*a[3]
                     + b[0]*b[0] + b[1]*b[1] + b[2]*b[2] + b[3]*b[3];
        }
#pragma unroll
        for (int tn = 0; tn < 4; ++tn)
#pragma unroll
            for (int tm = 0; tm < 4; ++tm)
                acc[tn][tm] = __builtin_amdgcn_mfma_f32_16x16x32_bf16(afr[tn], bfr[tm],
                                                                      acc[tn][tm], 0, 0, 0);
    }

    // ---- gallery inv-norms: complete each row's sumsq across the 4 quads.
    // Lane (qd,cc) holds k в [qd*8, qd*8+8) mod 32 for row m0+tm*16+cc;
    // xor 16/32 flip qd bits -> full sum, every lane gets its row's norm.
    float invg[4];
#pragma unroll
    for (int tm = 0; tm < 4; ++tm) {
        float s = gss[tm];
        s += __shfl_xor(s, 16, 64);
        s += __shfl_xor(s, 32, 64);
        invg[tm] = 1.f / fmaxf(sqrtf(s), 1e-8f);
    }

    // ---- epilogue: scale by invg, max over the 64 gallery cols, then invq.
    // C/D layout: row = qd*4 + r (query), col = cc (gallery).
    float* cmrow = cmax + ((size_t)l * NCHUNK + c) * N_Q;
#pragma unroll
    for (int tn = 0; tn < 4; ++tn) {
        const f32x4 iv4 = *(const f32x4*)(invq + l * N_Q + n0 + tn * 16 + qd * 4);
        f32x4 v4;
#pragma unroll
        for (int r = 0; r < 4; ++r) {
            float v = acc[tn][0][r] * invg[0];
            v = fmaxf(v, acc[tn][1][r] * invg[1]);
            v = fmaxf(v, acc[tn][2][r] * invg[2]);
            v = fmaxf(v, acc[tn][3][r] * invg[3]);
            // max over the 16 cols held across lanes (same qd group)
#pragma unroll
            for (int off = 8; off >= 1; off >>= 1) v = fmaxf(v, __shfl_xor(v, off, 64));
            v4[r] = v * iv4[r];   // invq > 0: monotone, applied after max
        }
        if (cc == 0) *(f32x4*)(cmrow + n0 + tn * 16 + qd * 4) = v4;
    }
}

// ---------------- reduce 800 chunk-maxes -> 8 segment-maxes per (l,n) ------
__global__ __launch_bounds__(256) void redc_kernel(const float* __restrict__ cmax,
                                                   float* __restrict__ pmax) {
    const int s = blockIdx.x;   // 0..7
    const int l = blockIdx.y;   // 0..3
    const int n = threadIdx.x;  // 0..255
    const float* p = cmax + ((size_t)l * NCHUNK + s * (NCHUNK / 8)) * N_Q + n;
    float m = -3e38f;
    for (int c = 0; c < NCHUNK / 8; ++c) m = fmaxf(m, p[(size_t)c * N_Q]);
    pmax[(l * 8 + s) * N_Q + n] = m;
}

// ---------------- final: mean over layers, 1 - sim, fp32 out --------------
__global__ __launch_bounds__(256) void final_kernel(const float* __restrict__ pmax,
                                                    float* __restrict__ out) {
    const int n = threadIdx.x;
    float sum = 0.f;
#pragma unroll
    for (int l = 0; l < 4; ++l) {
        float m = -3e38f;
#pragma unroll
        for (int s = 0; s < 8; ++s) m = fmaxf(m, pmax[(l * 8 + s) * N_Q + n]);
        sum += m;
    }
    out[n] = 1.0f - 0.25f * sum;
}

extern "C" void kernel_launch(void* const* d_in, const int* in_sizes, int n_in,
                              void* d_out, int out_size, void* d_ws, size_t ws_size,
                              hipStream_t stream) {
    const float* Q = (const float*)d_in[0];   // [4,256,1024] fp32
    const float* G = (const float*)d_in[1];   // [4,51200,1024] fp32
    float* out = (float*)d_out;               // 256 fp32

    float* invq = (float*)d_ws;                           // 1024 f
    float* cmax = invq + 1024;                            // 4*800*256 f = 3.125 MB
    float* pmax = cmax + (size_t)L_LAYERS * NCHUNK * N_Q; // 32*256 f
    // total ws use ~3.3 MB; every cell written before read (poison-safe)

    qnorm_kernel<<<dim3(L_LAYERS * N_Q), dim3(64), 0, stream>>>(Q, invq);
    sim_kernel<<<dim3(NCHUNK, L_LAYERS), dim3(256), 0, stream>>>(Q, G, invq, cmax);
    redc_kernel<<<dim3(8, L_LAYERS), dim3(256), 0, stream>>>(cmax, pmax);
    final_kernel<<<dim3(1), dim3(256), 0, stream>>>(pmax, out);
}